// Round 16
// baseline (6579.649 us; speedup 1.0000x reference)
//
#include <hip/hip_runtime.h>

// LureSystem recurrence, MI355X.
// R10: R9 (MFMA batch-16, 6.03 ms) was L2-stream-bound (384 KB weights/step
// = 130 GB/s/CU = the per-CU L2 ceiling) + 29.4M LDS bank conflicts (bad
// xT/wT swizzle: 8-way on ds_read_b128). Fixes:
// (1) C2+A per-wave slices = exactly 128 AGPRs (R7-proven resident cap),
//     consumed DIRECTLY as MFMA A-operands via inline asm ("a" constraint,
//     zero accvgpr_read, zero per-step traffic). Only B2 streams (128 KB/
//     step), issued at loop-top to overlap stage-1 MFMA.
// (2) Frag-major LDS layout for xT/wT/dT ([kt][lane][16B] = exact MFMA
//     B-fragment order): all ds_read_b128 lane-linear -> conflict-free;
//     writes are distinct-8B. Reduction buffers gone; 3 barriers/step.

#define NSTEP 2048

typedef _Float16 half_t;
typedef _Float16 half8 __attribute__((ext_vector_type(8)));
typedef _Float16 half4v __attribute__((ext_vector_type(4)));
typedef float f32x4 __attribute__((ext_vector_type(4)));

__device__ __forceinline__ f32x4 mfma16(half8 a, half8 b, f32x4 c) {
    return __builtin_amdgcn_mfma_f32_16x16x32_f16(a, b, c, 0, 0, 0);
}

__device__ __forceinline__ float tanh_fast(float p) {
    float ex = __expf(2.0f * p);
    return 1.0f - 2.0f / (ex + 1.0f);
}

// ---------------- prep: pack all weights into fragment order (ws) ----------
// frag(mt,kt): lane l supplies W[mt*16 + (l&15)][kt*32 + (l>>4)*8 + j], j=0..7
// tile = 64 lanes * 16B = 1024 B. ws tile ids:
//   C2: 0..127   A: 128..255   B2: 256..383          (M=256,K=256: mt*8+kt)
//   D21: 384..415  B: 416..447                        (M=256,K=64:  mt*2+kt)
//   C: 448..479    D12: 480..511                      (M=64, K=256: mt*8+kt)
//   D: 512..519                                       (M=64, K=64:  mt*2+kt)
__global__ __launch_bounds__(64)
void prep_kernel(const float* __restrict__ A_g, const float* __restrict__ B_g,
                 const float* __restrict__ B2_g, const float* __restrict__ C_g,
                 const float* __restrict__ D_g, const float* __restrict__ D12_g,
                 const float* __restrict__ C2_g, const float* __restrict__ D21_g,
                 half_t* __restrict__ ws)
{
    const int bid = blockIdx.x, l = threadIdx.x;
    const float* src; int Kdim, t;
    if      (bid < 128) { src = C2_g;  Kdim = 256; t = bid; }
    else if (bid < 256) { src = A_g;   Kdim = 256; t = bid - 128; }
    else if (bid < 384) { src = B2_g;  Kdim = 256; t = bid - 256; }
    else if (bid < 416) { src = D21_g; Kdim = 64;  t = bid - 384; }
    else if (bid < 448) { src = B_g;   Kdim = 64;  t = bid - 416; }
    else if (bid < 480) { src = C_g;   Kdim = 256; t = bid - 448; }
    else if (bid < 512) { src = D12_g; Kdim = 256; t = bid - 480; }
    else                { src = D_g;   Kdim = 64;  t = bid - 512; }
    const int ktiles = Kdim >> 5;
    const int mt = t / ktiles, kt = t - mt * ktiles;
    const int r = mt * 16 + (l & 15), c0 = kt * 32 + (l >> 4) * 8;
    const float* p = src + r * Kdim + c0;
    half_t* dst = ws + bid * 512 + l * 8;   // half units
#pragma unroll
    for (int j = 0; j < 8; ++j) dst[j] = (half_t)p[j];
}

// ---------------- main kernel ----------------
#define SW_D21 0
#define SW_B   32768
#define SW_C   65536
#define SW_D12 98304
#define SW_D   131072
#define XT_OFF 139264   // xT frag-major [8 kt][1024 B]
#define WT_OFF 147456   // wT frag-major [8 kt][1024 B]
#define DT_OFF 155648   // dT frag-major [2 buf][2 kt][1024 B]
#define LDS_TOTAL 159744

#define XOUT 33554432   // 256*2048*64
#define WOUT 33619968   // + 256*256

// 128-AGPR stash: v->a tie (compiler emits accvgpr_write; "a" uses keep class)
#define DECL8(P) half8 P##0, P##1, P##2, P##3, P##4, P##5, P##6, P##7;
#define TIEA(P, KT, base, MT) { \
    half8 t_ = *(const half8*)((base) + ((MT) * 8 + KT) * 512 + l * 8); \
    asm volatile("" : "=a"(P##KT) : "0"(t_)); }
#define INIT8A(P, base, MT) TIEA(P,0,base,MT) TIEA(P,1,base,MT) TIEA(P,2,base,MT) \
    TIEA(P,3,base,MT) TIEA(P,4,base,MT) TIEA(P,5,base,MT) TIEA(P,6,base,MT) TIEA(P,7,base,MT)

// MFMA with A-operand read straight from AGPR (no accvgpr_read)
#define MFMAW(acc, af, bf) \
    asm("v_mfma_f32_16x16x32_f16 %0, %1, %2, %0" : "+v"(acc) : "a"(af), "v"(bf));

#define STG1(KT) { \
    half8 xfk = *(const half8*)(smem + XT_OFF + (KT) * 1024 + (l << 4)); \
    MFMAW(accw0, c2_0##KT, xfk) MFMAW(accw1, c2_1##KT, xfk) \
    MFMAW(accx0, a_0##KT, xfk)  MFMAW(accx1, a_1##KT, xfk) }

#define LDB2(KT) \
    b2_0##KT = *(const half8*)(wB2 + (mt0 * 8 + KT) * 512 + l * 8); \
    b2_1##KT = *(const half8*)(wB2 + (mt1 * 8 + KT) * 512 + l * 8);

#define STG3(KT) { \
    half8 wfk = *(const half8*)(smem + WT_OFF + (KT) * 1024 + (l << 4)); \
    accx0 = mfma16(b2_0##KT, wfk, accx0); \
    accx1 = mfma16(b2_1##KT, wfk, accx1); }

__global__ __launch_bounds__(512)
void lure_kernel(const float* __restrict__ d_g, const float* __restrict__ x0_g,
                 const half_t* __restrict__ ws, float* __restrict__ out)
{
    __shared__ __align__(16) char smem[LDS_TOTAL];
    const int t = threadIdx.x, wid = t >> 6, l = t & 63;
    const int g = l & 15;        // batch column within frag
    const int q = l >> 4;        // quarter-wave row group
    const int bbase = blockIdx.x * 16;
    const int mt0 = wid * 2, mt1 = mt0 + 1;   // wave's M-tiles (M=256)

    const half_t* wC2 = ws;
    const half_t* wA  = ws + 128 * 512;
    const half_t* wB2 = ws + 256 * 512;

    // ---- AGPR stash: C2 + A slices (2 mt x 8 kt x 2 mats = 32 frags = 128 a)
    DECL8(c2_0) DECL8(c2_1) DECL8(a_0) DECL8(a_1)
    INIT8A(c2_0, wC2, mt0) INIT8A(c2_1, wC2, mt1)
    INIT8A(a_0,  wA,  mt0) INIT8A(a_1,  wA,  mt1)
    DECL8(b2_0) DECL8(b2_1)     // B2 stream frags (v-class, reloaded per step)

    // ---- copy small-weight frags ws -> LDS (136 KB)
    {
        const float4* src = (const float4*)(ws + 384 * 512);
        float4* dst = (float4*)smem;
        for (int i = t; i < 139264 / 16; i += 512) dst[i] = src[i];
    }
    // ---- xT init from x0 (frag-major)
    {
        int gg = t >> 5, mchunk = t & 31;
        const float* p = x0_g + (bbase + gg) * 256 + mchunk * 8;
        half8 v;
#pragma unroll
        for (int j = 0; j < 8; ++j) v[j] = (half_t)p[j];
        int l2 = ((mchunk & 3) << 4) | gg;
        *(half8*)(smem + XT_OFF + (mchunk >> 2) * 1024 + l2 * 16) = v;
    }
    // ---- d_0 -> dT[0] (waves 4-7)
    if (wid >= 4) {
        int u = t - 256, gg = u >> 4, c0 = (u & 15) * 4;
        float4 dv = *(const float4*)(d_g + ((bbase + gg) * NSTEP + 0) * 64 + c0);
        half4v h; h[0]=(half_t)dv.x; h[1]=(half_t)dv.y; h[2]=(half_t)dv.z; h[3]=(half_t)dv.w;
        int l2 = (((c0 >> 3) & 3) << 4) | gg;
        *(half4v*)(smem + DT_OFF + (c0 >> 5) * 1024 + l2 * 16 + (c0 & 7) * 2) = h;
    }
    __syncthreads();

    int cur = 0;
    for (int k = 0; k < NSTEP; ++k) {
        // ---- B2 stream for this step (16 x dwordx4; overlaps stage 1)
        LDB2(0) LDB2(1) LDB2(2) LDB2(3) LDB2(4) LDB2(5) LDB2(6) LDB2(7)

        // ---- prefetch d_{k+1} (waves 4-7)
        float4 dpf = {0.f, 0.f, 0.f, 0.f};
        if (wid >= 4) {
            int u = t - 256, gg = u >> 4, c0 = (u & 15) * 4;
            int kn = (k + 1 < NSTEP) ? k + 1 : NSTEP - 1;
            dpf = *(const float4*)(d_g + ((bbase + gg) * NSTEP + kn) * 64 + c0);
        }

        // ---- d_k frags (held through e-phase)
        half8 df0 = *(const half8*)(smem + DT_OFF + cur * 2048 + 0 * 1024 + (l << 4));
        half8 df1 = *(const half8*)(smem + DT_OFF + cur * 2048 + 1 * 1024 + (l << 4));

        // ---- stage 1: acc_w = C2.x + D21.d ; acc_x = A.x + B.d
        f32x4 accw0 = {0.f,0.f,0.f,0.f}, accw1 = {0.f,0.f,0.f,0.f};
        f32x4 accx0 = {0.f,0.f,0.f,0.f}, accx1 = {0.f,0.f,0.f,0.f};
        STG1(0) STG1(1) STG1(2) STG1(3) STG1(4) STG1(5) STG1(6) STG1(7)
#pragma unroll
        for (int kt = 0; kt < 2; ++kt) {
            half8 dd = kt ? df1 : df0;
            half8 m0 = *(const half8*)(smem + SW_D21 + (mt0 * 2 + kt) * 1024 + (l << 4));
            half8 m1 = *(const half8*)(smem + SW_D21 + (mt1 * 2 + kt) * 1024 + (l << 4));
            accw0 = mfma16(m0, dd, accw0);
            accw1 = mfma16(m1, dd, accw1);
            half8 b0 = *(const half8*)(smem + SW_B + (mt0 * 2 + kt) * 1024 + (l << 4));
            half8 b1 = *(const half8*)(smem + SW_B + (mt1 * 2 + kt) * 1024 + (l << 4));
            accx0 = mfma16(b0, dd, accx0);
            accx1 = mfma16(b1, dd, accx1);
        }

        // ---- stage 2: tanh -> wT frag-major (+ w_out at last step)
        {
            f32x4 w0, w1;
#pragma unroll
            for (int r = 0; r < 4; ++r) { w0[r] = tanh_fast(accw0[r]); w1[r] = tanh_fast(accw1[r]); }
            half4v h0, h1;
#pragma unroll
            for (int r = 0; r < 4; ++r) { h0[r] = (half_t)w0[r]; h1[r] = (half_t)w1[r]; }
            int l2a = (((mt0 & 1) * 2 + (q >> 1)) << 4) | g;
            int l2b = (((mt1 & 1) * 2 + (q >> 1)) << 4) | g;
            *(half4v*)(smem + WT_OFF + (mt0 >> 1) * 1024 + l2a * 16 + (q & 1) * 8) = h0;
            *(half4v*)(smem + WT_OFF + (mt1 >> 1) * 1024 + l2b * 16 + (q & 1) * 8) = h1;
            if (k == NSTEP - 1) {
                float4 f0 = {w0[0], w0[1], w0[2], w0[3]};
                float4 f1 = {w1[0], w1[1], w1[2], w1[3]};
                *(float4*)(out + WOUT + (bbase + g) * 256 + mt0 * 16 + q * 4) = f0;
                *(float4*)(out + WOUT + (bbase + g) * 256 + mt1 * 16 + q * 4) = f1;
            }
        }
        __syncthreads(); // B: wT complete

        // ---- stage 3: acc_x += B2.w ; x' -> xT frag-major (+ x_out last step)
        STG3(0) STG3(1) STG3(2) STG3(3) STG3(4) STG3(5) STG3(6) STG3(7)
        {
            half4v h0, h1;
#pragma unroll
            for (int r = 0; r < 4; ++r) { h0[r] = (half_t)accx0[r]; h1[r] = (half_t)accx1[r]; }
            int l2a = (((mt0 & 1) * 2 + (q >> 1)) << 4) | g;
            int l2b = (((mt1 & 1) * 2 + (q >> 1)) << 4) | g;
            *(half4v*)(smem + XT_OFF + (mt0 >> 1) * 1024 + l2a * 16 + (q & 1) * 8) = h0;
            *(half4v*)(smem + XT_OFF + (mt1 >> 1) * 1024 + l2b * 16 + (q & 1) * 8) = h1;
            if (k == NSTEP - 1) {
                float4 f0 = {accx0[0], accx0[1], accx0[2], accx0[3]};
                float4 f1 = {accx1[0], accx1[1], accx1[2], accx1[3]};
                *(float4*)(out + XOUT + (bbase + g) * 256 + mt0 * 16 + q * 4) = f0;
                *(float4*)(out + XOUT + (bbase + g) * 256 + mt1 * 16 + q * 4) = f1;
            }
        }
        __syncthreads(); // C: xT (x_{k+1}) complete

        // ---- stage 5: e = C.x' + D12.w + D.d (waves 0-3) | dT fill (waves 4-7)
        if (wid < 4) {
            f32x4 acce = {0.f,0.f,0.f,0.f};
#pragma unroll
            for (int kt = 0; kt < 8; ++kt) {
                half8 xfk = *(const half8*)(smem + XT_OFF + kt * 1024 + (l << 4));
                half8 cf  = *(const half8*)(smem + SW_C + (wid * 8 + kt) * 1024 + (l << 4));
                acce = mfma16(cf, xfk, acce);
                half8 wfk = *(const half8*)(smem + WT_OFF + kt * 1024 + (l << 4));
                half8 d12 = *(const half8*)(smem + SW_D12 + (wid * 8 + kt) * 1024 + (l << 4));
                acce = mfma16(d12, wfk, acce);
            }
#pragma unroll
            for (int kt = 0; kt < 2; ++kt) {
                half8 dfm = *(const half8*)(smem + SW_D + (wid * 2 + kt) * 1024 + (l << 4));
                acce = mfma16(dfm, kt ? df1 : df0, acce);
            }
            float4 fe = {acce[0], acce[1], acce[2], acce[3]};
            *(float4*)(out + ((bbase + g) * NSTEP + k) * 64 + wid * 16 + q * 4) = fe;
        } else {
            int u = t - 256, gg = u >> 4, c0 = (u & 15) * 4;
            half4v h; h[0]=(half_t)dpf.x; h[1]=(half_t)dpf.y; h[2]=(half_t)dpf.z; h[3]=(half_t)dpf.w;
            int l2 = (((c0 >> 3) & 3) << 4) | gg;
            *(half4v*)(smem + DT_OFF + (cur ^ 1) * 2048 + (c0 >> 5) * 1024 + l2 * 16 + (c0 & 7) * 2) = h;
        }
        __syncthreads(); // D
        cur ^= 1;
    }
}

extern "C" void kernel_launch(void* const* d_in, const int* in_sizes, int n_in,
                              void* d_out, int out_size, void* d_ws, size_t ws_size,
                              hipStream_t stream) {
    (void)in_sizes; (void)n_in; (void)out_size; (void)ws_size;
    const float* d_  = (const float*)d_in[0];
    const float* x0  = (const float*)d_in[1];
    const float* A   = (const float*)d_in[2];
    const float* B   = (const float*)d_in[3];
    const float* B2  = (const float*)d_in[4];
    const float* C   = (const float*)d_in[5];
    const float* D   = (const float*)d_in[6];
    const float* D12 = (const float*)d_in[7];
    const float* C2  = (const float*)d_in[8];
    const float* D21 = (const float*)d_in[9];
    float* out = (float*)d_out;
    half_t* ws = (half_t*)d_ws;

    hipLaunchKernelGGL(prep_kernel, dim3(520), dim3(64), 0, stream,
                       A, B, B2, C, D, D12, C2, D21, ws);
    hipLaunchKernelGGL(lure_kernel, dim3(16), dim3(512), 0, stream,
                       d_, x0, (const half_t*)ws, out);
}